// Round 1
// baseline (531.437 us; speedup 1.0000x reference)
//
#include <hip/hip_runtime.h>

typedef __bf16 bf16x8 __attribute__((ext_vector_type(8)));
typedef float f32x4 __attribute__((ext_vector_type(4)));
typedef unsigned short ushort8 __attribute__((ext_vector_type(8)));

__device__ __forceinline__ unsigned short f2bf(float f) {
  unsigned int u = __builtin_bit_cast(unsigned int, f);
  u += 0x7FFFu + ((u >> 16) & 1u);   // RNE
  return (unsigned short)(u >> 16);
}

// Pack conv_w (3,3,128,128 HWIO fp32) into MFMA B-fragment layout, bf16.
// pw frag (kt, nt): lane l holds B[k = kt*32 + (l>>4)*8 + j][oc = nt*16 + (l&15)],
// k = (u*3+v)*128 + c. 36 ktiles x 8 ntiles x 64 lanes x 8 bf16 = 294,912 B.
__global__ void pack_weights(const float* __restrict__ w, unsigned short* __restrict__ pw) {
  const int kt = blockIdx.x >> 3, nt = blockIdx.x & 7;
  const int l = threadIdx.x;
  const int tap = kt >> 2, cblk = kt & 3;
  const int c = cblk * 32 + ((l >> 4) << 3);
  const int oc = nt * 16 + (l & 15);
  ushort8 v;
#pragma unroll
  for (int j = 0; j < 8; ++j) {
    v[j] = f2bf(w[(tap * 128 + c + j) * 128 + oc]);
  }
  *(ushort8*)(pw + ((((kt << 3) + nt) * 64 + l) << 3)) = v;
}

// Fused: build y-tile (FIR'd 2x upsample) in LDS, then implicit-GEMM 3x3 conv.
// Block: out tile 16 rows x 32 cols x 128 oc. 8 waves, wave tile 128 pos x 64 oc.
__global__ __launch_bounds__(512, 2) void fused_up_conv(
    const float* __restrict__ x, const unsigned short* __restrict__ pw,
    const float* __restrict__ bias, float* __restrict__ out) {
  __shared__ __align__(16) char ylds[18 * 34 * 256];  // 153 KB: 18 rows x 34 cols x 128ch bf16

  const int blk = blockIdx.x;
  const int b  = blk >> 7;
  const int pt = (blk >> 3) & 15;
  const int qt = blk & 7;
  const int P = pt * 16, Q = qt * 32;
  const int tid = threadIdx.x;
  const float* xb = x + b * (128 * 128 * 128);

  // ---- Phase 1: build y tile ----
  // y[r] rows: r = P-1+rr, rr in [0,18); cols s = Q-1+ss, ss in [0,34).
  // y[r] (r even, r=2i): 0.75 x[i] + 0.25 x[i+1]; (odd): 0.25/0.75. Same per col.
  for (int pk = tid; pk < 18 * 34 * 16; pk += 512) {
    const int cp = pk & 15;
    const int rs = pk >> 4;
    const int ss = rs % 34;
    const int rr = rs / 34;
    const int r = P - 1 + rr;
    const int s = Q - 1 + ss;
    float v[8];
#pragma unroll
    for (int k = 0; k < 8; ++k) v[k] = 0.0f;
    if (r >= 0 && r < 256 && s >= 0 && s < 256) {
      const int i0 = r >> 1, j0 = s >> 1;
      const float wr1 = (r & 1) ? 0.75f : 0.25f;
      const float wc1 = (s & 1) ? 0.75f : 0.25f;
      const float wr0 = 1.0f - wr1, wc0 = 1.0f - wc1;
      const float w00 = wr0 * wc0, w01 = wr0 * wc1, w10 = wr1 * wc0, w11 = wr1 * wc1;
      const bool iok = i0 < 127, jok = j0 < 127;
      const float* p0 = xb + (i0 * 128 + j0) * 128 + cp * 8;
      const float4 z = {0.f, 0.f, 0.f, 0.f};
#pragma unroll
      for (int h = 0; h < 2; ++h) {
        float4 a00 = *(const float4*)(p0 + h * 4);
        float4 a01 = jok ? *(const float4*)(p0 + 128 + h * 4) : z;
        float4 a10 = iok ? *(const float4*)(p0 + 16384 + h * 4) : z;
        float4 a11 = (iok && jok) ? *(const float4*)(p0 + 16512 + h * 4) : z;
        v[h * 4 + 0] = w00 * a00.x + w01 * a01.x + w10 * a10.x + w11 * a11.x;
        v[h * 4 + 1] = w00 * a00.y + w01 * a01.y + w10 * a10.y + w11 * a11.y;
        v[h * 4 + 2] = w00 * a00.z + w01 * a01.z + w10 * a10.z + w11 * a11.z;
        v[h * 4 + 3] = w00 * a00.w + w01 * a01.w + w10 * a10.w + w11 * a11.w;
      }
    }
    ushort8 pk8;
#pragma unroll
    for (int k = 0; k < 8; ++k) pk8[k] = f2bf(v[k]);
    int byte_off = ((rr * 34 + ss) << 8) + (cp << 4);
    byte_off ^= (ss & 7) << 4;  // bank-conflict swizzle (write side)
    *(ushort8*)(ylds + byte_off) = pk8;
  }
  __syncthreads();

  // ---- Phase 2: K-loop, no barriers ----
  const int l15 = tid & 15;
  const int lh = (tid >> 4) & 3;
  const int lane = tid & 63;
  const int wid = tid >> 6;
  const int wm = wid >> 1;  // 0..3 : which 128-position group
  const int wn = wid & 1;   // 0..1 : which 64-oc group

  f32x4 acc[8][4] = {};

  int rowb[8], colb[8];
#pragma unroll
  for (int a = 0; a < 8; ++a) {
    const int mt = wm * 8 + a;          // m-tile index 0..31
    rowb[a] = mt >> 1;                  // out row within tile (oy)
    colb[a] = ((mt & 1) << 4) + l15;    // out col base + lane
  }
  const char* pwb = (const char*)pw + (wn * 256 + lane) * 16;

  for (int kt = 0; kt < 36; ++kt) {
    const int tap = kt >> 2, cblk = kt & 3;
    const int u = tap / 3, vv = tap - u * 3;
    bf16x8 af[8];
#pragma unroll
    for (int a = 0; a < 8; ++a) {
      const int ssv = colb[a] + vv;
      int byte_off = (((rowb[a] + u) * 34 + ssv) << 8) + ((cblk * 4 + lh) << 4);
      byte_off ^= (ssv & 7) << 4;  // same swizzle (read side)
      af[a] = *(const bf16x8*)(ylds + byte_off);
    }
    bf16x8 bfb[4];
#pragma unroll
    for (int n = 0; n < 4; ++n)
      bfb[n] = *(const bf16x8*)(pwb + kt * 8192 + n * 1024);
#pragma unroll
    for (int a = 0; a < 8; ++a)
#pragma unroll
      for (int n = 0; n < 4; ++n)
        acc[a][n] = __builtin_amdgcn_mfma_f32_16x16x32_bf16(af[a], bfb[n], acc[a][n], 0, 0, 0);
  }

  // ---- Epilogue: C/D layout col=lane&15, row=(lane>>4)*4+reg ----
  float bv[4];
#pragma unroll
  for (int n = 0; n < 4; ++n) bv[n] = bias[wn * 64 + n * 16 + l15];
  float* ob = out + b * (256 * 256 * 128);
#pragma unroll
  for (int a = 0; a < 8; ++a) {
    const int mt = wm * 8 + a;
    const int p = P + (mt >> 1);
    const int qb = Q + ((mt & 1) << 4) + lh * 4;
#pragma unroll
    for (int j = 0; j < 4; ++j) {
      float* orow = ob + (p * 256 + qb + j) * 128 + wn * 64 + l15;
#pragma unroll
      for (int n = 0; n < 4; ++n)
        orow[n * 16] = acc[a][n][j] + bv[n];
    }
  }
}

extern "C" void kernel_launch(void* const* d_in, const int* in_sizes, int n_in,
                              void* d_out, int out_size, void* d_ws, size_t ws_size,
                              hipStream_t stream) {
  const float* x = (const float*)d_in[0];
  const float* w = (const float*)d_in[1];
  const float* bias = (const float*)d_in[2];
  float* out = (float*)d_out;
  unsigned short* pw = (unsigned short*)d_ws;  // 294,912 B used

  pack_weights<<<dim3(288), dim3(64), 0, stream>>>(w, pw);
  fused_up_conv<<<dim3(1024), dim3(512), 0, stream>>>(x, pw, bias, out);
}

// Round 3
// 232.316 us; speedup vs baseline: 2.2876x; 2.2876x over previous
//
#include <hip/hip_runtime.h>

typedef __bf16 bf16x8 __attribute__((ext_vector_type(8)));
typedef float f32x4 __attribute__((ext_vector_type(4)));
typedef unsigned short ushort8 __attribute__((ext_vector_type(8)));

__device__ __forceinline__ unsigned short f2bf(float f) {
  unsigned int u = __builtin_bit_cast(unsigned int, f);
  u += 0x7FFFu + ((u >> 16) & 1u);   // RNE
  return (unsigned short)(u >> 16);
}

// Row/col blend coefficients: COEF[a][du][u] = weight of W-tap u on x-offset du
// for output phase a (valid for interior; borders fixed by fix_border).
__constant__ float COEF[2][3][3] = {
    {{0.25f, 0.00f, 0.00f},
     {0.75f, 0.75f, 0.25f},
     {0.00f, 0.25f, 0.75f}},
    {{0.75f, 0.25f, 0.00f},
     {0.25f, 0.75f, 0.75f},
     {0.00f, 0.00f, 0.25f}}
};

// Pack phase-blended weights into MFMA B-fragment layout, bf16.
__global__ void pack_weights(const float* __restrict__ w, unsigned short* __restrict__ pw) {
  const int kt = blockIdx.x >> 3, nt = blockIdx.x & 7;
  const int l = threadIdx.x;
  const int tap = kt >> 2, cblk = kt & 3;
  const int du = tap / 3, dv = tap - du * 3;
  const int c0 = cblk * 32 + ((l >> 4) << 3);
  const int oc = nt * 16 + (l & 15);
  float accp[4][8];
#pragma unroll
  for (int ph = 0; ph < 4; ++ph)
#pragma unroll
    for (int j = 0; j < 8; ++j) accp[ph][j] = 0.0f;
#pragma unroll
  for (int u = 0; u < 3; ++u)
#pragma unroll
    for (int v = 0; v < 3; ++v) {
      const float ra0 = COEF[0][du][u], ra1 = COEF[1][du][u];
      const float cb0 = COEF[0][dv][v], cb1 = COEF[1][dv][v];
      const float c00 = ra0 * cb0, c01 = ra0 * cb1, c10 = ra1 * cb0, c11 = ra1 * cb1;
#pragma unroll
      for (int j = 0; j < 8; ++j) {
        const float wv = w[((u * 3 + v) * 128 + c0 + j) * 128 + oc];
        accp[0][j] += c00 * wv;
        accp[1][j] += c01 * wv;
        accp[2][j] += c10 * wv;
        accp[3][j] += c11 * wv;
      }
    }
#pragma unroll
  for (int ph = 0; ph < 4; ++ph) {
    ushort8 o;
#pragma unroll
    for (int j = 0; j < 8; ++j) o[j] = f2bf(accp[ph][j]);
    *(ushort8*)(pw + ((((ph * 36 + kt) * 8 + nt) * 64 + l) << 3)) = o;
  }
}

// Main fused kernel (interior-exact; borders p==0 / q==0 overwritten by fix_border).
__global__ __launch_bounds__(512, 2) void fused_direct(
    const float* __restrict__ x, const unsigned short* __restrict__ pw,
    const float* __restrict__ bias, float* __restrict__ out) {
  __shared__ __align__(16) char xlds[19 * 11 * 256];  // 53,504 B

  const int blk = blockIdx.x;
  const int bimg = blk >> 7;
  const int it = (blk >> 4) & 7;
  const int jt = blk & 15;
  const int I0 = it * 16, J0 = jt * 8;
  const int tid = threadIdx.x;
  const float* xb = x + bimg * (128 * 128 * 128);

  for (int idx = tid; idx < 19 * 11 * 16; idx += 512) {
    const int cp = idx & 15;
    const int pos = idx >> 4;
    const int row = pos / 11;
    const int col = pos - row * 11;
    const int gi = I0 - 1 + row;
    const int gj = J0 - 1 + col;
    ushort8 u8 = {};
    if (((unsigned)gi < 128u) && ((unsigned)gj < 128u)) {
      const float* p = xb + ((gi << 7) + gj) * 128 + (cp << 3);
      const float4 A = *(const float4*)p;
      const float4 Bv = *(const float4*)(p + 4);
      u8[0] = f2bf(A.x); u8[1] = f2bf(A.y); u8[2] = f2bf(A.z); u8[3] = f2bf(A.w);
      u8[4] = f2bf(Bv.x); u8[5] = f2bf(Bv.y); u8[6] = f2bf(Bv.z); u8[7] = f2bf(Bv.w);
    }
    int byte = (pos << 8) + (cp << 4);
    byte ^= (pos & 7) << 4;
    *(ushort8*)(xlds + byte) = u8;
  }
  __syncthreads();

  const int l15 = tid & 15;
  const int lh = (tid >> 4) & 3;
  const int lane = tid & 63;
  const int wid = tid >> 6;
  const int a = (wid >> 2) & 1;
  const int b = (wid >> 1) & 1;
  const int nhalf = wid & 1;
  const int ph = a * 2 + b;

  f32x4 acc[8][4] = {};

  int pos0[8];
#pragma unroll
  for (int a_ = 0; a_ < 8; ++a_)
    pos0[a_] = (a_ * 2 + (l15 >> 3) + a) * 11 + (l15 & 7) + b;

  const char* pwb = (const char*)pw + ph * 294912 + nhalf * 4096 + lane * 16;

#define LOADB(buf, ktv)                                              \
  do {                                                               \
    _Pragma("unroll") for (int n = 0; n < 4; ++n)                    \
        buf[n] = *(const bf16x8*)(pwb + (ktv) * 8192 + n * 1024);    \
  } while (0)

#define BODY(ktv, buf)                                                          \
  do {                                                                          \
    const int tap_ = (ktv) >> 2, cblk_ = (ktv) & 3;                             \
    const int du_ = tap_ / 3, dv_ = tap_ - du_ * 3;                             \
    const int dpos_ = du_ * 11 + dv_;                                           \
    bf16x8 af[8];                                                               \
    _Pragma("unroll") for (int a_ = 0; a_ < 8; ++a_) {                          \
      const int posa = pos0[a_] + dpos_;                                        \
      int byte_ = (posa << 8) + ((cblk_ * 4 + lh) << 4);                        \
      byte_ ^= (posa & 7) << 4;                                                 \
      af[a_] = *(const bf16x8*)(xlds + byte_);                                  \
    }                                                                           \
    __builtin_amdgcn_s_setprio(1);                                              \
    _Pragma("unroll") for (int a_ = 0; a_ < 8; ++a_)                            \
        _Pragma("unroll") for (int n = 0; n < 4; ++n)                           \
            acc[a_][n] = __builtin_amdgcn_mfma_f32_16x16x32_bf16(               \
                af[a_], buf[n], acc[a_][n], 0, 0, 0);                           \
    __builtin_amdgcn_s_setprio(0);                                              \
  } while (0)

  bf16x8 bA[4], bB[4];
  LOADB(bA, 0);
#pragma unroll 1
  for (int kt = 0; kt < 34; kt += 2) {
    LOADB(bB, kt + 1);
    BODY(kt, bA);
    LOADB(bA, kt + 2);
    BODY(kt + 1, bB);
  }
  LOADB(bB, 35);
  BODY(34, bA);
  BODY(35, bB);

#undef LOADB
#undef BODY

  float bv[4];
#pragma unroll
  for (int n = 0; n < 4; ++n) bv[n] = bias[nhalf * 64 + n * 16 + l15];
  float* ob = out + bimg * (256 * 256 * 128) + nhalf * 64 + l15;
  const int P0 = it * 32 + a, Q0 = jt * 16 + b;
#pragma unroll
  for (int a_ = 0; a_ < 8; ++a_) {
#pragma unroll
    for (int jr = 0; jr < 4; ++jr) {
      const int mm = lh * 4 + jr;
      const int p = P0 + ((a_ * 2 + (mm >> 3)) << 1);
      const int q = Q0 + ((mm & 7) << 1);
      float* orow = ob + (p * 256 + q) * 128;
#pragma unroll
      for (int n = 0; n < 4; ++n) orow[n * 16] = acc[a_][n][jr] + bv[n];
    }
  }
}

// Exact recompute of border outputs: row p==0 (all q) and col q==0 (p>=1).
// y[r][s][c] = sum_{di,dj} h_{r&1}[di] h_{s&1}[dj] x[(r>>1)+di][(s>>1)+dj][c],
// h_0=[0.75,0.25], h_1=[0.25,0.75]; y index OOB -> 0 (conv pad), x OOB -> 0.
__global__ __launch_bounds__(256) void fix_border(
    const float* __restrict__ x, const float* __restrict__ w,
    const float* __restrict__ bias, float* __restrict__ out) {
  __shared__ float yw[2 * 128 * 34];  // [f][c][ws], 34.8 KB

  const int blk = blockIdx.x;
  const int ocg = blk & 1;
  const int chunk = (blk >> 1) & 7;
  const int type = (blk >> 4) & 1;  // 0: row border p=0; 1: col border q=0
  const int bi = blk >> 5;
  const int base0 = chunk * 32;
  const int tid = threadIdx.x;
  const float* xb = x + bi * (128 * 128 * 128);

  for (int idx = tid; idx < 2 * 128 * 34; idx += 256) {
    const int ws = idx % 34;
    const int cf = idx / 34;
    const int c = cf & 127;
    const int f = cf >> 7;
    const int t = base0 - 1 + ws;  // coordinate along the border axis
    float val = 0.0f;
    if (t >= 0 && t < 256) {
      const int t0 = t >> 1;
      const float hA0 = (t & 1) ? 0.25f : 0.75f;  // blend coeff of offset 0
      const float hA1 = 1.0f - hA0;
      const float hF0 = f ? 0.25f : 0.75f;        // fixed-axis (r or s = f)
      const float hF1 = 1.0f - hF0;
      if (type == 0) {
        // fixed rows 0,1 ; col coord t
        const bool ok1 = (t0 + 1) < 128;
        const float v00 = xb[(t0) * 128 + c];                         // x[0][t0]
        const float v01 = ok1 ? xb[(t0 + 1) * 128 + c] : 0.0f;        // x[0][t0+1]
        const float v10 = xb[(128 + t0) * 128 + c];                   // x[1][t0]
        const float v11 = ok1 ? xb[(128 + t0 + 1) * 128 + c] : 0.0f;  // x[1][t0+1]
        val = hF0 * (hA0 * v00 + hA1 * v01) + hF1 * (hA0 * v10 + hA1 * v11);
      } else {
        // fixed cols 0,1 ; row coord t
        const bool okr1 = (t0 + 1) < 128;
        const float v00 = xb[(t0 * 128) * 128 + c];                          // x[t0][0]
        const float v01 = xb[(t0 * 128 + 1) * 128 + c];                      // x[t0][1]
        const float v10 = okr1 ? xb[((t0 + 1) * 128) * 128 + c] : 0.0f;      // x[t0+1][0]
        const float v11 = okr1 ? xb[((t0 + 1) * 128 + 1) * 128 + c] : 0.0f;  // x[t0+1][1]
        val = hA0 * (hF0 * v00 + hF1 * v01) + hA1 * (hF0 * v10 + hF1 * v11);
      }
    }
    yw[(f * 128 + c) * 34 + ws] = val;
  }
  __syncthreads();

  const int lane = tid & 63;
  const int wv = tid >> 6;
  const int ch = lane >> 5;   // c half
  const int ql = lane & 31;   // position within chunk
  const int oc0 = ocg * 64 + wv * 16;

  float acc[16];
#pragma unroll
  for (int j = 0; j < 16; ++j) acc[j] = 0.0f;

  // type 0: out[0][q] = sum_{u in {1,2}, v in {0,1,2}} W[u][v] . y[u-1][q+v-1]
  // type 1: out[p][0] = sum_{u in {0,1,2}, v in {1,2}} W[u][v] . y[p+u-1][v-1]
#pragma unroll 2
  for (int c0 = 0; c0 < 64; ++c0) {
    const int c = ch * 64 + c0;
#pragma unroll
    for (int tf = 0; tf < 2; ++tf) {
#pragma unroll
      for (int tb = 0; tb < 3; ++tb) {
        const float yv = yw[(tf * 128 + c) * 34 + (ql + tb)];
        const int uu = (type == 0) ? (tf + 1) : tb;
        const int vv = (type == 0) ? tb : (tf + 1);
        const float* wp = w + ((uu * 3 + vv) * 128 + c) * 128 + oc0;
#pragma unroll
        for (int j = 0; j < 16; j += 4) {
          const float4 w4 = *(const float4*)(wp + j);
          acc[j + 0] += yv * w4.x;
          acc[j + 1] += yv * w4.y;
          acc[j + 2] += yv * w4.z;
          acc[j + 3] += yv * w4.w;
        }
      }
    }
  }
#pragma unroll
  for (int j = 0; j < 16; ++j) acc[j] += __shfl_xor(acc[j], 32, 64);

  const int pos = base0 + ql;
  if (ch == 0 && !(type == 1 && pos == 0)) {
    const int p = (type == 0) ? 0 : pos;
    const int q = (type == 0) ? pos : 0;
    float* op = out + bi * (256 * 256 * 128) + (p * 256 + q) * 128 + oc0;
#pragma unroll
    for (int j = 0; j < 16; ++j) op[j] = acc[j] + bias[oc0 + j];
  }
}

extern "C" void kernel_launch(void* const* d_in, const int* in_sizes, int n_in,
                              void* d_out, int out_size, void* d_ws, size_t ws_size,
                              hipStream_t stream) {
  const float* x = (const float*)d_in[0];
  const float* w = (const float*)d_in[1];
  const float* bias = (const float*)d_in[2];
  float* out = (float*)d_out;
  unsigned short* pw = (unsigned short*)d_ws;  // 1,179,648 B used

  pack_weights<<<dim3(288), dim3(64), 0, stream>>>(w, pw);
  fused_direct<<<dim3(1024), dim3(512), 0, stream>>>(x, pw, bias, out);
  fix_border<<<dim3(256), dim3(256), 0, stream>>>(x, w, bias, out);
}